// Round 10
// baseline (859.016 us; speedup 1.0000x reference)
//
#include <hip/hip_runtime.h>
#include <math.h>

// Problem constants
#define NB 2048   // batch
#define NIN 512   // input width
#define NK 16     // K (patch/channel width)
#define NL 497    // L = IN - K + 1
#define NT 96     // decode steps
#define NREP 32   // BN accumulator replicas

// ---------- math helpers ----------
__device__ __forceinline__ float gelu_exact(float x) {
    return 0.5f * x * (1.0f + erff(x * 0.70710678118654752440f));
}
__device__ __forceinline__ float gate_act(float acc, bool isG) {
    float mm = isG ? 2.0f : 1.0f;
    float e  = __expf(-mm * acc);
    float s  = 1.0f / (1.0f + e);
    return isG ? 2.0f * s - 1.0f : s;
}
__device__ __forceinline__ float tanh_safe(float x) {
    float t = __expf(-2.0f * fabsf(x));
    float r = 1.0f - 2.0f * t / (1.0f + t);
    return copysignf(r, x);
}
__device__ __forceinline__ void load16(const float* __restrict__ ptr, float* dst) {
    const float4* rp = (const float4*)ptr;
    float4 a = rp[0], b = rp[1], c = rp[2], d = rp[3];
    dst[0]=a.x; dst[1]=a.y; dst[2]=a.z;  dst[3]=a.w;
    dst[4]=b.x; dst[5]=b.y; dst[6]=b.z;  dst[7]=b.w;
    dst[8]=c.x; dst[9]=c.y; dst[10]=c.z; dst[11]=c.w;
    dst[12]=d.x;dst[13]=d.y;dst[14]=d.z; dst[15]=d.w;
}

// ---------- K1: patch + seg matmul + gelu + BN partial sums (round-3/7 known-good) ----------
__global__ __launch_bounds__(256) void k_seg(
    const float* __restrict__ x, const float* __restrict__ pe,
    const float* __restrict__ Wseg, const float* __restrict__ bseg,
    float* __restrict__ p, float* __restrict__ p_last, float* __restrict__ bn)
{
    __shared__ float xs[NIN];
    __shared__ float wsg[NK * NK];
    __shared__ float bs[NK];
    const int tid = threadIdx.x;
    const int b = blockIdx.x;
    float* bnr = bn + (size_t)(b & (NREP - 1)) * 1024;
    for (int i = tid; i < NIN; i += 256) xs[i] = x[(size_t)b * NIN + i];
    if (tid < NK * NK) wsg[tid] = Wseg[tid];
    if (tid < NK) bs[tid] = bseg[tid];
    __syncthreads();

    for (int l = tid; l < NL; l += 256) {
        float u[NK];
        load16(pe + l * NK, u);
        #pragma unroll
        for (int k = 0; k < NK; k++) u[k] += xs[l + k];
        float p16[NK];
        float s = 0.f, s2 = 0.f;
        #pragma unroll
        for (int k = 0; k < NK; k++) {
            float acc = bs[k];
            #pragma unroll
            for (int kp = 0; kp < NK; kp++) acc += u[kp] * wsg[k * NK + kp];
            float gv = gelu_exact(acc);
            p16[k] = gv; s += gv; s2 += gv * gv;
        }
        float4* pr = (float4*)(p + ((size_t)b * NL + l) * NK);
        pr[0] = make_float4(p16[0], p16[1], p16[2], p16[3]);
        pr[1] = make_float4(p16[4], p16[5], p16[6], p16[7]);
        pr[2] = make_float4(p16[8], p16[9], p16[10], p16[11]);
        pr[3] = make_float4(p16[12], p16[13], p16[14], p16[15]);
        atomicAdd(&bnr[l], s);
        atomicAdd(&bnr[512 + l], s2);
        if (l == NL - 1) {
            float4* pl = (float4*)(p_last + (size_t)b * NK);
            pl[0] = pr[0]; pl[1] = pr[1]; pl[2] = pr[2]; pl[3] = pr[3];
        }
    }
}

// ---------- K2: finalize BN -> ansh4 pairs: [4l]={a_f,sh_f}(l), [4l+2]={a_b,sh_b}(l) ----------
// a_b(s) = a(NL-1-s): both directions read pair[2s+d] with ASCENDING step s.
__global__ void k_bnfin(const float* __restrict__ bn, const float* __restrict__ gbn,
                        const float* __restrict__ bbn, float* __restrict__ ansh4)
{
    int l = blockIdx.x * blockDim.x + threadIdx.x;
    if (l < NL) {
        float s = 0.f, s2 = 0.f;
        #pragma unroll 4
        for (int r = 0; r < NREP; r++) {
            s  += bn[(size_t)r * 1024 + l];
            s2 += bn[(size_t)r * 1024 + 512 + l];
        }
        const float inv = 1.0f / (float)(NB * NK);
        float mu  = s * inv;
        float var = s2 * inv - mu * mu;
        float rr  = rsqrtf(var + 1e-5f);
        float av  = gbn[l] * rr;
        float sh  = bbn[l] - mu * av;
        ansh4[4 * l]     = av;
        ansh4[4 * l + 1] = sh;
        int lr = NL - 1 - l;
        ansh4[4 * lr + 2] = av;
        ansh4[4 * lr + 3] = sh;
    }
}

// ---------- K3: LSTM sweep, 8 batch elements per wave ----------
// lane = bh*8 + u: bh = batch sub-index (0..7), u = hidden unit (0..7).
// Each lane computes ALL FOUR gates (i,f,g,o) of unit u for batch b = tile*8+bh:
// no gate exchange, no divergence. h shared across the 8-lane unit group by a
// 7-shuffle butterfly allgather; recurrent weights pre-permuted per lane
// (whh4[gate][m] = Whh[row][u^m]) so butterfly-ordered hx[m]=h[u^m] dots directly.
// Wave -> (tile, direction): waveid = blockIdx*4 + warp; d = waveid&1; tile = waveid>>1.
// MODE 1: input p rows + BN affine (layer 0).  MODE 2: input o0 rows (layer 1).
template<int MODE, int WRITE_O, int WRITE_LAST>
__global__ __launch_bounds__(256) void k_lstm8(
    const float* __restrict__ src, const float* __restrict__ ansh4,
    const float* __restrict__ WihF, const float* __restrict__ WhhF,
    const float* __restrict__ WihB, const float* __restrict__ WhhB,
    float* __restrict__ oout, float* __restrict__ st, float* __restrict__ oblast)
{
    const int tid = threadIdx.x;
    const int waveid = blockIdx.x * 4 + (tid >> 6);
    const int lane = tid & 63;
    const int d = waveid & 1;
    const int tile = waveid >> 1;
    const int bh = lane >> 3;
    const int u  = lane & 7;
    const int b  = tile * 8 + bh;

    const float* Wih = d ? WihB : WihF;
    const float* Whh = d ? WhhB : WhhF;

    // per-lane weights: 4 gate rows of unit u (rows u, u+8, u+16, u+24)
    float wih4[4][16], whh4[4][8], Sg4[4];
    #pragma unroll
    for (int gq = 0; gq < 4; gq++) {
        const int row = (gq << 3) + u;
        #pragma unroll
        for (int k = 0; k < 16; k++) wih4[gq][k] = Wih[row * 16 + k];
        #pragma unroll
        for (int m = 0; m < 8; m++)  whh4[gq][m] = Whh[row * 8 + (u ^ m)];
        float sg = 0.f;
        if constexpr (MODE == 1) {
            #pragma unroll
            for (int k = 0; k < 16; k++) sg += wih4[gq][k];
        }
        Sg4[gq] = sg;
    }

    float c = 0.f;
    float hx[8];   // hx[m] = h[u^m] (butterfly order), fully static indexing
    #pragma unroll
    for (int m = 0; m < 8; m++) hx[m] = 0.f;

    const int t0 = d ? NL - 1 : 0;
    float* po = nullptr;
    const int dstore = d ? -NK : NK;
    if constexpr (WRITE_O) po = oout + ((size_t)b * NL + t0) * NK + (d << 3) + u;

    auto stp = [&](int s, const float* B, float2 a) {
        float d0 = 0.f, d1 = 0.f, d2 = 0.f, d3 = 0.f;
        #pragma unroll
        for (int k = 0; k < 16; k++) {
            d0 += B[k] * wih4[0][k]; d1 += B[k] * wih4[1][k];
            d2 += B[k] * wih4[2][k]; d3 += B[k] * wih4[3][k];
        }
        if constexpr (MODE == 1) {
            d0 = a.x * d0 + a.y * Sg4[0]; d1 = a.x * d1 + a.y * Sg4[1];
            d2 = a.x * d2 + a.y * Sg4[2]; d3 = a.x * d3 + a.y * Sg4[3];
        }
        #pragma unroll
        for (int m = 0; m < 8; m++) {
            d0 += whh4[0][m] * hx[m]; d1 += whh4[1][m] * hx[m];
            d2 += whh4[2][m] * hx[m]; d3 += whh4[3][m] * hx[m];
        }
        float si = gate_act(d0, false);
        float sf = gate_act(d1, false);
        float tg = gate_act(d2, true);
        float so = gate_act(d3, false);
        float cn = sf * c + si * tg;
        float hn = so * tanh_safe(cn);
        c = cn;
        // butterfly allgather: hx[m] = h[u^m]
        float n0 = hn;
        float n1 = __shfl_xor(n0, 1, 64);
        float n2 = __shfl_xor(n0, 2, 64);
        float n3 = __shfl_xor(n1, 2, 64);
        float n4 = __shfl_xor(n0, 4, 64);
        float n5 = __shfl_xor(n1, 4, 64);
        float n6 = __shfl_xor(n2, 4, 64);
        float n7 = __shfl_xor(n3, 4, 64);
        hx[0] = n0; hx[1] = n1; hx[2] = n2; hx[3] = n3;
        hx[4] = n4; hx[5] = n5; hx[6] = n6; hx[7] = n7;
        if constexpr (WRITE_O) { *po = hn; po += dstore; }
        if constexpr (WRITE_LAST) {
            if (s == 0 && d == 1) oblast[b * 8 + u] = hn;
        }
    };

    // 4-deep register pipeline over rows (clamped prefetch, round-3 pattern)
    const float* srcb = src + (size_t)b * NL * NK;
    auto rowt = [&](int sp) -> int {
        int t = d ? (NL - 1 - sp) : sp;
        t = t < 0 ? 0 : t;
        t = t > NL - 1 ? NL - 1 : t;
        return t;
    };
    auto ld = [&](int sp, float* dst, float2& a) {
        const int t = rowt(sp);
        load16(srcb + (size_t)t * NK, dst);
        if constexpr (MODE == 1) {
            int sc = sp > NL - 1 ? NL - 1 : sp;
            a = ((const float2*)ansh4)[2 * sc + d];
        }
    };
    float B0[16], B1[16], B2[16], B3[16];
    float2 A0{0,0}, A1{0,0}, A2{0,0}, A3{0,0};
    ld(0, B0, A0); ld(1, B1, A1); ld(2, B2, A2);
    int s = 0;
    for (; s + 4 <= NL; s += 4) {
        ld(s + 3, B3, A3); stp(s + 0, B0, A0);
        ld(s + 4, B0, A0); stp(s + 1, B1, A1);
        ld(s + 5, B1, A1); stp(s + 2, B2, A2);
        ld(s + 6, B2, A2); stp(s + 3, B3, A3);
    }
    if (s     < NL) stp(s,     B0, A0);
    if (s + 1 < NL) stp(s + 1, B1, A1);
    if (s + 2 < NL) stp(s + 2, B2, A2);

    // final states: every lane owns (b, u) of direction d
    float* hs = st + (d ? (size_t)2 * NB * 8 : 0);
    hs[b * 8 + u] = hx[0];
    hs[(size_t)NB * 8 + b * 8 + u] = c;
}

// ---------- K4: 96-step decode recurrence (round-7 shfl version, known good) ----------
__global__ __launch_bounds__(256) void k_dec(
    const float* __restrict__ Wf0, const float* __restrict__ Uf0,
    const float* __restrict__ Wb0, const float* __restrict__ Ub0,
    const float* __restrict__ Wf1, const float* __restrict__ Uf1,
    const float* __restrict__ Wb1, const float* __restrict__ Ub1,
    const float* __restrict__ st0, const float* __restrict__ st1,
    const float* __restrict__ oblast, const float* __restrict__ p_last,
    const float* __restrict__ ansh4,
    const float* __restrict__ gln, const float* __restrict__ bln,
    float* __restrict__ z)
{
    const int tid = threadIdx.x, lane = tid & 63;
    const int b = blockIdx.x * 4 + (tid >> 6);
    const int d = lane >> 5, g = lane & 31, j = g & 7, base = d << 5;
    const float* Wih0 = d ? Wb0 : Wf0; const float* Whh0 = d ? Ub0 : Uf0;
    const float* Wih1 = d ? Wb1 : Wf1; const float* Whh1 = d ? Ub1 : Uf1;
    float wih0[16], whh0[8], wih1[16], whh1[8];
    #pragma unroll
    for (int k = 0; k < 16; k++) { wih0[k] = Wih0[g * 16 + k]; wih1[k] = Wih1[g * 16 + k]; }
    #pragma unroll
    for (int k = 0; k < 8; k++)  { whh0[k] = Whh0[g * 8 + k]; whh1[k] = Whh1[g * 8 + k]; }

    float h0 = 0.f, c0 = 0.f, h1 = 0.f, c1 = 0.f;
    if (g < 8) {
        const float* s0 = st0 + (d ? (size_t)2 * NB * 8 : 0);
        h0 = s0[b * 8 + j]; c0 = s0[(size_t)NB * 8 + b * 8 + j];
        const float* s1 = st1 + (d ? (size_t)2 * NB * 8 : 0);
        h1 = s1[b * 8 + j]; c1 = s1[(size_t)NB * 8 + b * 8 + j];
    }

    // fb = LN(concat(hf1_final, ob1_last)) * g_ln + b_ln + xe[:,L-1,:]
    float fb[16];
    {
        float ol[16];
        #pragma unroll
        for (int k = 0; k < 8; k++) ol[k] = st1[b * 8 + k];          // hF1 final == of1[:,L-1]
        #pragma unroll
        for (int k = 0; k < 8; k++) ol[8 + k] = oblast[b * 8 + k];   // ob1[:,L-1]
        float mn = 0.f;
        #pragma unroll
        for (int k = 0; k < 16; k++) mn += ol[k];
        mn *= (1.0f / 16.0f);
        float vv = 0.f;
        #pragma unroll
        for (int k = 0; k < 16; k++) { float dq = ol[k] - mn; vv += dq * dq; }
        vv *= (1.0f / 16.0f);
        float rr = rsqrtf(vv + 1e-5f);
        float aL = ansh4[4 * (NL - 1)], sL = ansh4[4 * (NL - 1) + 1];
        const float* prow = p_last + (size_t)b * NK;
        #pragma unroll
        for (int k = 0; k < 16; k++)
            fb[k] = (ol[k] - mn) * rr * gln[k] + bln[k] + (prow[k] * aL + sL);
    }

    const bool isG = (g >= 16) && (g < 24);
    for (int t = 0; t < NT; t++) {
        // layer-0 cell
        float acc = 0.f;
        #pragma unroll
        for (int k = 0; k < 16; k++) acc += fb[k] * wih0[k];
        #pragma unroll
        for (int k = 0; k < 8; k++) acc += whh0[k] * __shfl(h0, base + k, 64);
        float val = gate_act(acc, isG);
        float fv = __shfl(val, lane + 8, 64);
        float gv = __shfl(val, lane + 16, 64);
        float ov = __shfl(val, lane + 24, 64);
        float cn = fv * c0 + val * gv;
        float hn = ov * tanh_safe(cn);
        if (g < 8) { c0 = cn; h0 = hn; }
        // m0 = concat(hf0, hb0) broadcast to all lanes
        float m0[16];
        #pragma unroll
        for (int k = 0; k < 16; k++) m0[k] = __shfl(h0, k < 8 ? k : 24 + k, 64);
        // layer-1 cell
        acc = 0.f;
        #pragma unroll
        for (int k = 0; k < 16; k++) acc += m0[k] * wih1[k];
        #pragma unroll
        for (int k = 0; k < 8; k++) acc += whh1[k] * __shfl(h1, base + k, 64);
        val = gate_act(acc, isG);
        fv = __shfl(val, lane + 8, 64);
        gv = __shfl(val, lane + 16, 64);
        ov = __shfl(val, lane + 24, 64);
        cn = fv * c1 + val * gv;
        hn = ov * tanh_safe(cn);
        if (g < 8) { c1 = cn; h1 = hn; }
        if (g < 8) z[((size_t)b * NT + t) * NK + (d << 3) + j] = hn;
        // new fb = raw o = concat(hf1, hb1)
        #pragma unroll
        for (int k = 0; k < 16; k++) fb[k] = __shfl(h1, k < 8 ? k : 24 + k, 64);
    }
}

// ---------- K5: decoder MLP over all (b,t) rows ----------
__global__ __launch_bounds__(256) void k_head(
    const float* __restrict__ z, const float* __restrict__ gln, const float* __restrict__ bln,
    const float* __restrict__ W1, const float* __restrict__ b1,
    const float* __restrict__ W2, const float* __restrict__ b2,
    float* __restrict__ outp)
{
    __shared__ float w1s[512 * 16];
    __shared__ float b1s[512];
    __shared__ float w2s[512];
    const int tid = threadIdx.x;
    for (int i = tid; i < 512 * 16 / 4; i += 256)
        ((float4*)w1s)[i] = ((const float4*)W1)[i];
    for (int i = tid; i < 512; i += 256) { b1s[i] = b1[i]; w2s[i] = W2[i]; }
    __syncthreads();

    const size_t r = (size_t)blockIdx.x * 256 + tid;   // r = b*NT + t
    float zr[16];
    load16(z + r * 16, zr);
    float mn = 0.f;
    #pragma unroll
    for (int k = 0; k < 16; k++) mn += zr[k];
    mn *= (1.0f / 16.0f);
    float vv = 0.f;
    #pragma unroll
    for (int k = 0; k < 16; k++) { float dq = zr[k] - mn; vv += dq * dq; }
    vv *= (1.0f / 16.0f);
    float rr = rsqrtf(vv + 1e-5f);
    float zn[16];
    #pragma unroll
    for (int k = 0; k < 16; k++) zn[k] = (zr[k] - mn) * rr * gln[k] + bln[k];

    float y = b2[0];
    #pragma unroll 2
    for (int i = 0; i < 512; i++) {
        const float4* w4 = (const float4*)&w1s[i * 16];
        float4 wa = w4[0], wb = w4[1], wc = w4[2], wd = w4[3];
        float acc = b1s[i];
        acc += zn[0]*wa.x + zn[1]*wa.y + zn[2]*wa.z + zn[3]*wa.w;
        acc += zn[4]*wb.x + zn[5]*wb.y + zn[6]*wb.z + zn[7]*wb.w;
        acc += zn[8]*wc.x + zn[9]*wc.y + zn[10]*wc.z + zn[11]*wc.w;
        acc += zn[12]*wd.x + zn[13]*wd.y + zn[14]*wd.z + zn[15]*wd.w;
        y += gelu_exact(acc) * w2s[i];
    }
    outp[r] = y;
}

// ---------- launcher ----------
extern "C" void kernel_launch(void* const* d_in, const int* in_sizes, int n_in,
                              void* d_out, int out_size, void* d_ws, size_t ws_size,
                              hipStream_t stream)
{
    const float* x    = (const float*)d_in[0];
    const float* pe   = (const float*)d_in[1];
    const float* Wseg = (const float*)d_in[2];
    const float* bseg = (const float*)d_in[3];
    const float* gbn  = (const float*)d_in[4];
    const float* bbn  = (const float*)d_in[5];
    const float* Wf0  = (const float*)d_in[6];
    const float* Uf0  = (const float*)d_in[7];
    const float* Wb0  = (const float*)d_in[8];
    const float* Ub0  = (const float*)d_in[9];
    const float* Wf1  = (const float*)d_in[10];
    const float* Uf1  = (const float*)d_in[11];
    const float* Wb1  = (const float*)d_in[12];
    const float* Ub1  = (const float*)d_in[13];
    const float* gln  = (const float*)d_in[14];
    const float* bln  = (const float*)d_in[15];
    const float* W1   = (const float*)d_in[16];
    const float* b1   = (const float*)d_in[17];
    const float* W2   = (const float*)d_in[18];
    const float* b2   = (const float*)d_in[19];

    const size_t SZ_BN    = (size_t)NREP * 1024 * 4;
    const size_t SZ_ANSH  = (size_t)4 * 512 * 4;
    const size_t SZ_ST    = (size_t)4 * NB * 8 * 4;
    const size_t SZ_OBL   = (size_t)NB * 8 * 4;
    const size_t SZ_PLAST = (size_t)NB * NK * 4;
    const size_t SZ_Z     = (size_t)NB * NT * NK * 4;
    const size_t SZ_P     = (size_t)NB * NL * NK * 4;

    char* ws = (char*)d_ws;
    size_t off = 0;
    auto take = [&](size_t bytes) -> char* {
        char* r = ws + off;
        off = (off + bytes + 255) & ~(size_t)255;
        return r;
    };
    float* bn     = (float*)take(SZ_BN);
    float* ansh4  = (float*)take(SZ_ANSH);
    float* st0    = (float*)take(SZ_ST);
    float* st1    = (float*)take(SZ_ST);
    float* obl    = (float*)take(SZ_OBL);
    float* p_last = (float*)take(SZ_PLAST);
    float* z      = (float*)take(SZ_Z);
    float* p      = (float*)take(SZ_P);    // 65.1 MB
    float* o0     = (float*)take(SZ_P);    // 65.1 MB

    hipMemsetAsync(bn, 0, SZ_BN, stream);
    k_seg<<<NB, 256, 0, stream>>>(x, pe, Wseg, bseg, p, p_last, bn);
    k_bnfin<<<2, 256, 0, stream>>>(bn, gbn, bbn, ansh4);
    // 512 waves per sweep: 2048 batch / 8 per wave * 2 directions; 4 waves/block
    k_lstm8<1, 1, 0><<<128, 256, 0, stream>>>(p, ansh4, Wf0, Uf0, Wb0, Ub0, o0, st0, nullptr);
    k_lstm8<2, 0, 1><<<128, 256, 0, stream>>>(o0, ansh4, Wf1, Uf1, Wb1, Ub1, nullptr, st1, obl);
    k_dec<<<NB / 4, 256, 0, stream>>>(Wf0, Uf0, Wb0, Ub0, Wf1, Uf1, Wb1, Ub1,
                                      st0, st1, obl, p_last, ansh4, gln, bln, z);
    k_head<<<(NB * NT) / 256, 256, 0, stream>>>(z, gln, bln, W1, b1, W2, b2, (float*)d_out);
}

// Round 11
// 736.004 us; speedup vs baseline: 1.1671x; 1.1671x over previous
//
#include <hip/hip_runtime.h>
#include <math.h>

// Problem constants
#define NB 2048   // batch
#define NIN 512   // input width
#define NK 16     // K (patch/channel width)
#define NL 497    // L = IN - K + 1
#define NT 96     // decode steps
#define NREP 32   // BN accumulator replicas

// ---------- math helpers ----------
__device__ __forceinline__ float gelu_exact(float x) {
    return 0.5f * x * (1.0f + erff(x * 0.70710678118654752440f));
}
__device__ __forceinline__ float gate_act(float acc, bool isG) {
    float mm = isG ? 2.0f : 1.0f;
    float e  = __expf(-mm * acc);
    float s  = 1.0f / (1.0f + e);
    return isG ? 2.0f * s - 1.0f : s;
}
__device__ __forceinline__ float tanh_safe(float x) {
    float t = __expf(-2.0f * fabsf(x));
    float r = 1.0f - 2.0f * t / (1.0f + t);
    return copysignf(r, x);
}
__device__ __forceinline__ float bperm(int idxb, float v) {
    return __int_as_float(__builtin_amdgcn_ds_bpermute(idxb, __float_as_int(v)));
}
__device__ __forceinline__ void load16(const float* __restrict__ ptr, float* dst) {
    const float4* rp = (const float4*)ptr;
    float4 a = rp[0], b = rp[1], c = rp[2], d = rp[3];
    dst[0]=a.x; dst[1]=a.y; dst[2]=a.z;  dst[3]=a.w;
    dst[4]=b.x; dst[5]=b.y; dst[6]=b.z;  dst[7]=b.w;
    dst[8]=c.x; dst[9]=c.y; dst[10]=c.z; dst[11]=c.w;
    dst[12]=d.x;dst[13]=d.y;dst[14]=d.z; dst[15]=d.w;
}

// ---------- K1: patch + seg matmul + gelu + BN sums (+ optional layer-0 praw) ----------
// praw layout: [b][l][d][u][gate] float4-per-(d,u); bwd stored l-reversed so both
// directions stream ascending addresses in the sweep.
template<int PRAW>
__global__ __launch_bounds__(256) void k_seg(
    const float* __restrict__ x, const float* __restrict__ pe,
    const float* __restrict__ Wseg, const float* __restrict__ bseg,
    const float* __restrict__ Wf0, const float* __restrict__ Wb0,
    float* __restrict__ praw, float* __restrict__ pfull,
    float* __restrict__ p_last, float* __restrict__ bn)
{
    __shared__ float xs[NIN];
    __shared__ float wsg[NK * NK];
    __shared__ float bs[NK];
    __shared__ float wf[32 * 16];
    __shared__ float wb[32 * 16];
    const int tid = threadIdx.x;
    const int b = blockIdx.x;
    float* bnr = bn + (size_t)(b & (NREP - 1)) * 1024;
    for (int i = tid; i < NIN; i += 256) xs[i] = x[(size_t)b * NIN + i];
    if (tid < NK * NK) wsg[tid] = Wseg[tid];
    if (tid < NK) bs[tid] = bseg[tid];
    if constexpr (PRAW) {
        for (int i = tid; i < 512; i += 256) { wf[i] = Wf0[i]; wb[i] = Wb0[i]; }
    }
    __syncthreads();

    for (int l = tid; l < NL; l += 256) {
        float u[NK];
        load16(pe + l * NK, u);
        #pragma unroll
        for (int k = 0; k < NK; k++) u[k] += xs[l + k];
        float p16[NK];
        float s = 0.f, s2 = 0.f;
        #pragma unroll
        for (int k = 0; k < NK; k++) {
            float acc = bs[k];
            #pragma unroll
            for (int kp = 0; kp < NK; kp++) acc += u[kp] * wsg[k * NK + kp];
            float gv = gelu_exact(acc);
            p16[k] = gv; s += gv; s2 += gv * gv;
        }
        atomicAdd(&bnr[l], s);
        atomicAdd(&bnr[512 + l], s2);

        if constexpr (PRAW) {
            // fwd: [b][l][0][u][gate] ; bwd: [b][NL-1-l][1][u][gate]
            float4* pf = (float4*)(praw + (((size_t)b * NL + l) * 2 + 0) * 32);
            float4* pb = (float4*)(praw + (((size_t)b * NL + (NL - 1 - l)) * 2 + 1) * 32);
            #pragma unroll 2
            for (int uu = 0; uu < 8; uu++) {
                float4 of, ob;
                float* ofp = (float*)&of;
                float* obp = (float*)&ob;
                #pragma unroll
                for (int gq = 0; gq < 4; gq++) {
                    const float* wrf = &wf[(gq * 8 + uu) * 16];
                    const float* wrb = &wb[(gq * 8 + uu) * 16];
                    float a0 = 0.f, a1 = 0.f;
                    #pragma unroll
                    for (int k = 0; k < 16; k++) { a0 += p16[k] * wrf[k]; a1 += p16[k] * wrb[k]; }
                    ofp[gq] = a0; obp[gq] = a1;
                }
                pf[uu] = of; pb[uu] = ob;
            }
        } else {
            float4* pr = (float4*)(pfull + ((size_t)b * NL + l) * NK);
            pr[0] = make_float4(p16[0], p16[1], p16[2], p16[3]);
            pr[1] = make_float4(p16[4], p16[5], p16[6], p16[7]);
            pr[2] = make_float4(p16[8], p16[9], p16[10], p16[11]);
            pr[3] = make_float4(p16[12], p16[13], p16[14], p16[15]);
        }
        if (l == NL - 1) {
            float4* pl = (float4*)(p_last + (size_t)b * NK);
            pl[0] = make_float4(p16[0], p16[1], p16[2], p16[3]);
            pl[1] = make_float4(p16[4], p16[5], p16[6], p16[7]);
            pl[2] = make_float4(p16[8], p16[9], p16[10], p16[11]);
            pl[3] = make_float4(p16[12], p16[13], p16[14], p16[15]);
        }
    }
}

// ---------- K2: finalize BN -> ansh4 pairs: [4l]={a_f,sh_f}(l), [4l+2]={a_b,sh_b} ----------
__global__ void k_bnfin(const float* __restrict__ bn, const float* __restrict__ gbn,
                        const float* __restrict__ bbn, float* __restrict__ ansh4)
{
    int l = blockIdx.x * blockDim.x + threadIdx.x;
    if (l < NL) {
        float s = 0.f, s2 = 0.f;
        #pragma unroll 4
        for (int r = 0; r < NREP; r++) {
            s  += bn[(size_t)r * 1024 + l];
            s2 += bn[(size_t)r * 1024 + 512 + l];
        }
        const float inv = 1.0f / (float)(NB * NK);
        float mu  = s * inv;
        float var = s2 * inv - mu * mu;
        float rr  = rsqrtf(var + 1e-5f);
        float av  = gbn[l] * rr;
        float sh  = bbn[l] - mu * av;
        ansh4[4 * l]     = av;
        ansh4[4 * l + 1] = sh;
        int lr = NL - 1 - l;
        ansh4[4 * lr + 2] = av;
        ansh4[4 * lr + 3] = sh;
    }
}

// ---------- K_proj: layer-1 input projections o0 @ [Wf1;Wb1]^T -> praw ----------
__global__ __launch_bounds__(256) void k_proj(
    const float* __restrict__ o0, const float* __restrict__ Wf1,
    const float* __restrict__ Wb1, float* __restrict__ praw)
{
    __shared__ float wf[512], wb[512];
    const int tid = threadIdx.x;
    const int b = blockIdx.x;
    for (int i = tid; i < 512; i += 256) { wf[i] = Wf1[i]; wb[i] = Wb1[i]; }
    __syncthreads();
    for (int l = tid; l < NL; l += 256) {
        float v[16];
        load16(o0 + ((size_t)b * NL + l) * NK, v);
        float4* pf = (float4*)(praw + (((size_t)b * NL + l) * 2 + 0) * 32);
        float4* pb = (float4*)(praw + (((size_t)b * NL + (NL - 1 - l)) * 2 + 1) * 32);
        #pragma unroll 2
        for (int uu = 0; uu < 8; uu++) {
            float4 of, ob;
            float* ofp = (float*)&of;
            float* obp = (float*)&ob;
            #pragma unroll
            for (int gq = 0; gq < 4; gq++) {
                const float* wrf = &wf[(gq * 8 + uu) * 16];
                const float* wrb = &wb[(gq * 8 + uu) * 16];
                float a0 = 0.f, a1 = 0.f;
                #pragma unroll
                for (int k = 0; k < 16; k++) { a0 += v[k] * wrf[k]; a1 += v[k] * wrb[k]; }
                ofp[gq] = a0; obp[gq] = a1;
            }
            pf[uu] = of; pb[uu] = ob;
        }
    }
}

// ---------- K3 (praw path): LSTM sweep, 8 chains/wave, praw input ----------
// lane = bh*8+u. Each lane: all 4 gates of unit u for batch b = tile*8+bh.
// Input: 1 float4/lane/step (precomputed gate dots). Recurrent weights
// pre-permuted (whh4[g][m] = Whh[row][u^m]); hx[m]=h[u^m] via 7 INDEPENDENT
// ds_bpermute (depth-1 latency). MODE 1: +BN affine (Sg from Wih). MODE 2: plain.
template<int MODE, int WRITE_O, int WRITE_LAST>
__global__ __launch_bounds__(64) void k_lstm8p(
    const float* __restrict__ praw, const float* __restrict__ ansh4,
    const float* __restrict__ WihF, const float* __restrict__ WihB,
    const float* __restrict__ WhhF, const float* __restrict__ WhhB,
    float* __restrict__ oout, float* __restrict__ st, float* __restrict__ oblast)
{
    const int waveid = blockIdx.x;          // 512 blocks x 64 threads = 512 waves
    const int lane = threadIdx.x;
    const int d = waveid & 1;
    const int tile = waveid >> 1;
    const int bh = lane >> 3, u = lane & 7;
    const int b = tile * 8 + bh;

    const float* Whh = d ? WhhB : WhhF;
    float whh4[4][8];
    #pragma unroll
    for (int gq = 0; gq < 4; gq++) {
        const int row = (gq << 3) + u;
        #pragma unroll
        for (int m = 0; m < 8; m++) whh4[gq][m] = Whh[row * 8 + (u ^ m)];
    }
    float Sg4[4] = {0.f, 0.f, 0.f, 0.f};
    if constexpr (MODE == 1) {
        const float* Wih = d ? WihB : WihF;
        #pragma unroll
        for (int gq = 0; gq < 4; gq++) {
            const int row = (gq << 3) + u;
            float sg = 0.f;
            #pragma unroll
            for (int k = 0; k < 16; k++) sg += Wih[row * 16 + k];
            Sg4[gq] = sg;
        }
    }
    // byte indices for independent bpermute gathers (m = 1..7)
    int bidx[8];
    #pragma unroll
    for (int m = 0; m < 8; m++) bidx[m] = ((lane & 56) | (u ^ m)) << 2;

    float c = 0.f;
    float hx[8];
    #pragma unroll
    for (int m = 0; m < 8; m++) hx[m] = 0.f;

    float* po = nullptr;
    const int dst = d ? -NK : NK;
    if constexpr (WRITE_O) po = oout + ((size_t)b * NL + (d ? NL - 1 : 0)) * NK + (d << 3) + u;

    auto cell = [&](float4 P, float2 a, int s) {
        float a0, a1, a2, a3;
        if constexpr (MODE == 1) {
            a0 = a.x * P.x + a.y * Sg4[0];
            a1 = a.x * P.y + a.y * Sg4[1];
            a2 = a.x * P.z + a.y * Sg4[2];
            a3 = a.x * P.w + a.y * Sg4[3];
        } else {
            a0 = P.x; a1 = P.y; a2 = P.z; a3 = P.w;
        }
        #pragma unroll
        for (int m = 0; m < 8; m++) {
            a0 += whh4[0][m] * hx[m]; a1 += whh4[1][m] * hx[m];
            a2 += whh4[2][m] * hx[m]; a3 += whh4[3][m] * hx[m];
        }
        float si = gate_act(a0, false);
        float sf = gate_act(a1, false);
        float tg = gate_act(a2, true);
        float so = gate_act(a3, false);
        float cn = sf * c + si * tg;
        float hn = so * tanh_safe(cn);
        c = cn;
        hx[0] = hn;
        hx[1] = bperm(bidx[1], hn);
        hx[2] = bperm(bidx[2], hn);
        hx[3] = bperm(bidx[3], hn);
        hx[4] = bperm(bidx[4], hn);
        hx[5] = bperm(bidx[5], hn);
        hx[6] = bperm(bidx[6], hn);
        hx[7] = bperm(bidx[7], hn);
        if constexpr (WRITE_O) { *po = hn; po += dst; }
        if constexpr (WRITE_LAST) {
            if (s == 0 && d == 1) oblast[b * 8 + u] = hn;
        }
    };

    // streams: praw float4 at index ((b*NL+l)*2+d)*8+u ; step delta = 16 float4s
    const float4* pr = (const float4*)praw + (((size_t)b * NL * 2) + d) * 8 + u;
    const float2* pa = (const float2*)ansh4 + d;   // pa[2s] = (a, sh) for step s
    float4 P0, P1, P2, P3;
    float2 A0{0,0}, A1{0,0}, A2{0,0}, A3{0,0};
    P0 = pr[0];  P1 = pr[16]; P2 = pr[32];
    if constexpr (MODE == 1) { A0 = pa[0]; A1 = pa[2]; A2 = pa[4]; }
    pr += 48; pa += 6;
    int s = 0;
    for (; s + 4 <= NL; s += 4) {
        P3 = pr[0];  if constexpr (MODE == 1) A3 = pa[0]; cell(P0, A0, s);
        P0 = pr[16]; if constexpr (MODE == 1) A0 = pa[2]; cell(P1, A1, s + 1);
        P1 = pr[32]; if constexpr (MODE == 1) A1 = pa[4]; cell(P2, A2, s + 2);
        P2 = pr[48]; if constexpr (MODE == 1) A2 = pa[6]; cell(P3, A3, s + 3);
        pr += 64; pa += 8;
    }
    if (s     < NL) cell(P0, A0, s);
    if (s + 1 < NL) cell(P1, A1, s + 1);
    if (s + 2 < NL) cell(P2, A2, s + 2);

    float* hs = st + (d ? (size_t)2 * NB * 8 : 0);
    hs[b * 8 + u] = hx[0];
    hs[(size_t)NB * 8 + b * 8 + u] = c;
}

// ---------- K3 (fallback): round-7 layout-A sweep (known good) ----------
template<int MODE, int WRITE_O, int WRITE_LAST>
__global__ __launch_bounds__(256) void k_lstmA(
    const float* __restrict__ src, const float* __restrict__ ansh4,
    const float* __restrict__ WihF, const float* __restrict__ WhhF,
    const float* __restrict__ WihB, const float* __restrict__ WhhB,
    float* __restrict__ oout, float* __restrict__ st, float* __restrict__ oblast)
{
    const int tid = threadIdx.x;
    const int lane = tid & 63;
    const int b = blockIdx.x * 4 + (tid >> 6);
    const int d = lane >> 5, g = lane & 31, j = g & 7;
    const int base = d << 5;
    const float* Wih = d ? WihB : WihF;
    const float* Whh = d ? WhhB : WhhF;
    float whh[8];
    #pragma unroll
    for (int k = 0; k < 8; k++) whh[k] = Whh[g * 8 + k];
    float wih[16];
    float Sg = 0.f;
    #pragma unroll
    for (int k = 0; k < 16; k++) wih[k] = Wih[g * 16 + k];
    if constexpr (MODE == 1) {
        #pragma unroll
        for (int k = 0; k < 16; k++) Sg += wih[k];
    }
    float h = 0.f, c = 0.f;
    const bool isG = (g >= 16) && (g < 24);
    auto cell = [&](float acc, int s) {
        #pragma unroll
        for (int k = 0; k < 8; k++) acc += whh[k] * __shfl(h, base + k, 64);
        float val = gate_act(acc, isG);
        float fv = __shfl(val, lane + 8, 64);
        float gv = __shfl(val, lane + 16, 64);
        float ov = __shfl(val, lane + 24, 64);
        float cn = fv * c + val * gv;
        float hn = ov * tanh_safe(cn);
        if (g < 8) { c = cn; h = hn; }
        if constexpr (WRITE_O) {
            const int t = d ? (NL - 1 - s) : s;
            if (g < 8) oout[((size_t)b * NL + t) * NK + (d << 3) + j] = hn;
        }
        if constexpr (WRITE_LAST) {
            if (s == 0 && d == 1 && g < 8) oblast[b * 8 + j] = hn;
        }
    };
    const float* srcb = src + (size_t)b * NL * NK;
    auto rowt = [&](int sp) -> int {
        int t = d ? (NL - 1 - sp) : sp;
        t = t < 0 ? 0 : t;
        t = t > NL - 1 ? NL - 1 : t;
        return t;
    };
    auto ld = [&](int sp, float* dstv, float2& a) {
        const int t = rowt(sp);
        load16(srcb + (size_t)t * NK, dstv);
        if constexpr (MODE == 1) {
            int sc = sp > NL - 1 ? NL - 1 : sp;
            a = ((const float2*)ansh4)[2 * sc + d];
        }
    };
    auto stp = [&](int s, const float* B, float2 a) {
        float acc = 0.f;
        #pragma unroll
        for (int k = 0; k < 16; k++) acc += B[k] * wih[k];
        if constexpr (MODE == 1) acc = a.x * acc + a.y * Sg;
        cell(acc, s);
    };
    float B0[16], B1[16], B2[16], B3[16];
    float2 A0{0,0}, A1{0,0}, A2{0,0}, A3{0,0};
    ld(0, B0, A0); ld(1, B1, A1); ld(2, B2, A2);
    int s = 0;
    for (; s + 4 <= NL; s += 4) {
        ld(s + 3, B3, A3); stp(s + 0, B0, A0);
        ld(s + 4, B0, A0); stp(s + 1, B1, A1);
        ld(s + 5, B1, A1); stp(s + 2, B2, A2);
        ld(s + 6, B2, A2); stp(s + 3, B3, A3);
    }
    if (s     < NL) stp(s,     B0, A0);
    if (s + 1 < NL) stp(s + 1, B1, A1);
    if (s + 2 < NL) stp(s + 2, B2, A2);
    if (g < 8) {
        float* hs = st + (d ? (size_t)2 * NB * 8 : 0);
        hs[b * 8 + j] = h;
        hs[(size_t)NB * 8 + b * 8 + j] = c;
    }
}

// ---------- K4: 96-step decode recurrence (round-7, known good) ----------
__global__ __launch_bounds__(256) void k_dec(
    const float* __restrict__ Wf0, const float* __restrict__ Uf0,
    const float* __restrict__ Wb0, const float* __restrict__ Ub0,
    const float* __restrict__ Wf1, const float* __restrict__ Uf1,
    const float* __restrict__ Wb1, const float* __restrict__ Ub1,
    const float* __restrict__ st0, const float* __restrict__ st1,
    const float* __restrict__ oblast, const float* __restrict__ p_last,
    const float* __restrict__ ansh4,
    const float* __restrict__ gln, const float* __restrict__ bln,
    float* __restrict__ z)
{
    const int tid = threadIdx.x, lane = tid & 63;
    const int b = blockIdx.x * 4 + (tid >> 6);
    const int d = lane >> 5, g = lane & 31, j = g & 7, base = d << 5;
    const float* Wih0 = d ? Wb0 : Wf0; const float* Whh0 = d ? Ub0 : Uf0;
    const float* Wih1 = d ? Wb1 : Wf1; const float* Whh1 = d ? Ub1 : Uf1;
    float wih0[16], whh0[8], wih1[16], whh1[8];
    #pragma unroll
    for (int k = 0; k < 16; k++) { wih0[k] = Wih0[g * 16 + k]; wih1[k] = Wih1[g * 16 + k]; }
    #pragma unroll
    for (int k = 0; k < 8; k++)  { whh0[k] = Whh0[g * 8 + k]; whh1[k] = Whh1[g * 8 + k]; }

    float h0 = 0.f, c0 = 0.f, h1 = 0.f, c1 = 0.f;
    if (g < 8) {
        const float* s0 = st0 + (d ? (size_t)2 * NB * 8 : 0);
        h0 = s0[b * 8 + j]; c0 = s0[(size_t)NB * 8 + b * 8 + j];
        const float* s1 = st1 + (d ? (size_t)2 * NB * 8 : 0);
        h1 = s1[b * 8 + j]; c1 = s1[(size_t)NB * 8 + b * 8 + j];
    }

    float fb[16];
    {
        float ol[16];
        #pragma unroll
        for (int k = 0; k < 8; k++) ol[k] = st1[b * 8 + k];
        #pragma unroll
        for (int k = 0; k < 8; k++) ol[8 + k] = oblast[b * 8 + k];
        float mn = 0.f;
        #pragma unroll
        for (int k = 0; k < 16; k++) mn += ol[k];
        mn *= (1.0f / 16.0f);
        float vv = 0.f;
        #pragma unroll
        for (int k = 0; k < 16; k++) { float dq = ol[k] - mn; vv += dq * dq; }
        vv *= (1.0f / 16.0f);
        float rr = rsqrtf(vv + 1e-5f);
        float aL = ansh4[4 * (NL - 1)], sL = ansh4[4 * (NL - 1) + 1];
        const float* prow = p_last + (size_t)b * NK;
        #pragma unroll
        for (int k = 0; k < 16; k++)
            fb[k] = (ol[k] - mn) * rr * gln[k] + bln[k] + (prow[k] * aL + sL);
    }

    const bool isG = (g >= 16) && (g < 24);
    for (int t = 0; t < NT; t++) {
        float acc = 0.f;
        #pragma unroll
        for (int k = 0; k < 16; k++) acc += fb[k] * wih0[k];
        #pragma unroll
        for (int k = 0; k < 8; k++) acc += whh0[k] * __shfl(h0, base + k, 64);
        float val = gate_act(acc, isG);
        float fv = __shfl(val, lane + 8, 64);
        float gv = __shfl(val, lane + 16, 64);
        float ov = __shfl(val, lane + 24, 64);
        float cn = fv * c0 + val * gv;
        float hn = ov * tanh_safe(cn);
        if (g < 8) { c0 = cn; h0 = hn; }
        float m0[16];
        #pragma unroll
        for (int k = 0; k < 16; k++) m0[k] = __shfl(h0, k < 8 ? k : 24 + k, 64);
        acc = 0.f;
        #pragma unroll
        for (int k = 0; k < 16; k++) acc += m0[k] * wih1[k];
        #pragma unroll
        for (int k = 0; k < 8; k++) acc += whh1[k] * __shfl(h1, base + k, 64);
        val = gate_act(acc, isG);
        fv = __shfl(val, lane + 8, 64);
        gv = __shfl(val, lane + 16, 64);
        ov = __shfl(val, lane + 24, 64);
        cn = fv * c1 + val * gv;
        hn = ov * tanh_safe(cn);
        if (g < 8) { c1 = cn; h1 = hn; }
        if (g < 8) z[((size_t)b * NT + t) * NK + (d << 3) + j] = hn;
        #pragma unroll
        for (int k = 0; k < 16; k++) fb[k] = __shfl(h1, k < 8 ? k : 24 + k, 64);
    }
}

// ---------- K5: decoder MLP over all (b,t) rows ----------
__global__ __launch_bounds__(256) void k_head(
    const float* __restrict__ z, const float* __restrict__ gln, const float* __restrict__ bln,
    const float* __restrict__ W1, const float* __restrict__ b1,
    const float* __restrict__ W2, const float* __restrict__ b2,
    float* __restrict__ outp)
{
    __shared__ float w1s[512 * 16];
    __shared__ float b1s[512];
    __shared__ float w2s[512];
    const int tid = threadIdx.x;
    for (int i = tid; i < 512 * 16 / 4; i += 256)
        ((float4*)w1s)[i] = ((const float4*)W1)[i];
    for (int i = tid; i < 512; i += 256) { b1s[i] = b1[i]; w2s[i] = W2[i]; }
    __syncthreads();

    const size_t r = (size_t)blockIdx.x * 256 + tid;
    float zr[16];
    load16(z + r * 16, zr);
    float mn = 0.f;
    #pragma unroll
    for (int k = 0; k < 16; k++) mn += zr[k];
    mn *= (1.0f / 16.0f);
    float vv = 0.f;
    #pragma unroll
    for (int k = 0; k < 16; k++) { float dq = zr[k] - mn; vv += dq * dq; }
    vv *= (1.0f / 16.0f);
    float rr = rsqrtf(vv + 1e-5f);
    float zn[16];
    #pragma unroll
    for (int k = 0; k < 16; k++) zn[k] = (zr[k] - mn) * rr * gln[k] + bln[k];

    float y = b2[0];
    #pragma unroll 2
    for (int i = 0; i < 512; i++) {
        const float4* w4 = (const float4*)&w1s[i * 16];
        float4 wa = w4[0], wb = w4[1], wc = w4[2], wd = w4[3];
        float acc = b1s[i];
        acc += zn[0]*wa.x + zn[1]*wa.y + zn[2]*wa.z + zn[3]*wa.w;
        acc += zn[4]*wb.x + zn[5]*wb.y + zn[6]*wb.z + zn[7]*wb.w;
        acc += zn[8]*wc.x + zn[9]*wc.y + zn[10]*wc.z + zn[11]*wc.w;
        acc += zn[12]*wd.x + zn[13]*wd.y + zn[14]*wd.z + zn[15]*wd.w;
        y += gelu_exact(acc) * w2s[i];
    }
    outp[r] = y;
}

// ---------- launcher ----------
extern "C" void kernel_launch(void* const* d_in, const int* in_sizes, int n_in,
                              void* d_out, int out_size, void* d_ws, size_t ws_size,
                              hipStream_t stream)
{
    const float* x    = (const float*)d_in[0];
    const float* pe   = (const float*)d_in[1];
    const float* Wseg = (const float*)d_in[2];
    const float* bseg = (const float*)d_in[3];
    const float* gbn  = (const float*)d_in[4];
    const float* bbn  = (const float*)d_in[5];
    const float* Wf0  = (const float*)d_in[6];
    const float* Uf0  = (const float*)d_in[7];
    const float* Wb0  = (const float*)d_in[8];
    const float* Ub0  = (const float*)d_in[9];
    const float* Wf1  = (const float*)d_in[10];
    const float* Uf1  = (const float*)d_in[11];
    const float* Wb1  = (const float*)d_in[12];
    const float* Ub1  = (const float*)d_in[13];
    const float* gln  = (const float*)d_in[14];
    const float* bln  = (const float*)d_in[15];
    const float* W1   = (const float*)d_in[16];
    const float* b1   = (const float*)d_in[17];
    const float* W2   = (const float*)d_in[18];
    const float* b2   = (const float*)d_in[19];

    const size_t SZ_BN    = (size_t)NREP * 1024 * 4;
    const size_t SZ_ANSH  = (size_t)4 * 512 * 4;
    const size_t SZ_ST    = (size_t)4 * NB * 8 * 4;
    const size_t SZ_OBL   = (size_t)NB * 8 * 4;
    const size_t SZ_PLAST = (size_t)NB * NK * 4;
    const size_t SZ_Z     = (size_t)NB * NT * NK * 4;
    const size_t SZ_P     = (size_t)NB * NL * NK * 4;    // 65.1 MB (p or o0 rows)
    const size_t SZ_PRAW  = (size_t)NB * NL * 64 * 4;    // 260.6 MB
    const size_t GUARD    = 8192;

    char* ws = (char*)d_ws;
    size_t off = 0;
    auto take = [&](size_t bytes) -> char* {
        char* r = ws + off;
        off = (off + bytes + 255) & ~(size_t)255;
        return r;
    };
    float* bn     = (float*)take(SZ_BN);
    float* ansh4  = (float*)take(SZ_ANSH);
    float* st0    = (float*)take(SZ_ST);
    float* st1    = (float*)take(SZ_ST);
    float* obl    = (float*)take(SZ_OBL);
    float* p_last = (float*)take(SZ_PLAST);
    float* z      = (float*)take(SZ_Z);

    const size_t fixed = off;
    const size_t need_praw = fixed + SZ_P + SZ_PRAW + GUARD + 2048;
    const bool use_praw = (ws_size >= need_praw);

    hipMemsetAsync(bn, 0, SZ_BN, stream);

    if (use_praw) {
        float* o0   = (float*)take(SZ_P);
        float* praw = (float*)take(SZ_PRAW);
        (void)take(GUARD);
        k_seg<1><<<NB, 256, 0, stream>>>(x, pe, Wseg, bseg, Wf0, Wb0, praw, nullptr, p_last, bn);
        k_bnfin<<<2, 256, 0, stream>>>(bn, gbn, bbn, ansh4);
        k_lstm8p<1, 1, 0><<<512, 64, 0, stream>>>(praw, ansh4, Wf0, Wb0, Uf0, Ub0, o0, st0, nullptr);
        k_proj<<<NB, 256, 0, stream>>>(o0, Wf1, Wb1, praw);
        k_lstm8p<2, 0, 1><<<512, 64, 0, stream>>>(praw, nullptr, nullptr, nullptr, Uf1, Ub1, nullptr, st1, obl);
    } else {
        float* p  = (float*)take(SZ_P);
        float* o0 = (float*)take(SZ_P);
        (void)take(GUARD);
        k_seg<0><<<NB, 256, 0, stream>>>(x, pe, Wseg, bseg, Wf0, Wb0, nullptr, p, p_last, bn);
        k_bnfin<<<2, 256, 0, stream>>>(bn, gbn, bbn, ansh4);
        k_lstmA<1, 1, 0><<<NB / 4, 256, 0, stream>>>(p, ansh4, Wf0, Uf0, Wb0, Ub0, o0, st0, nullptr);
        k_lstmA<2, 0, 1><<<NB / 4, 256, 0, stream>>>(o0, ansh4, Wf1, Uf1, Wb1, Ub1, nullptr, st1, obl);
    }
    k_dec<<<NB / 4, 256, 0, stream>>>(Wf0, Uf0, Wb0, Ub0, Wf1, Uf1, Wb1, Ub1,
                                      st0, st1, obl, p_last, ansh4, gln, bln, z);
    k_head<<<(NB * NT) / 256, 256, 0, stream>>>(z, gln, bln, W1, b1, W2, b2, (float*)d_out);
}